// Round 1
// baseline (301.762 us; speedup 1.0000x reference)
//
#include <hip/hip_runtime.h>

#define N 96
#define NNN (N * N * N)
#define C_CH 32

// tile geometry: block 8x8x4 = 256 threads, each thread computes 2 voxels along w
// VX=2 (not 4): acc[27][2]=54 regs keeps unified VGPR+AGPR footprint < 128
// -> 16 waves/CU (was ~190 regs -> 8 waves/CU at VX=4)
#define TXD 8
#define TYD 8
#define TZD 4
#define VX 2
#define TW (TXD * VX)          // 16
#define TH TYD                 // 8
#define TD TZD                 // 4

// halo tile in LDS: 18 x 10 x 6, row padded to 20 (bank stride 20 -> ty groups
// spread over all even banks, <=2-way aliasing = free; 8B-aligned float2 reads)
#define HWS 20
#define HH 10
#define HD 6
#define PLANE (HWS * HH)       // 200
#define HTOT (PLANE * HD)      // 1200
#define NTH (TXD * TYD * TZD)  // 256
#define NR ((HTOT + NTH - 1) / NTH)  // 5 staging rounds
#define SMSZ (NR * NTH)        // 1280 (over-allocated so stores are unconditional)

__global__ __launch_bounds__(NTH, 4) void wincorr_kernel(
    const float* __restrict__ fixedp,
    const float* __restrict__ movingp,
    float* __restrict__ outp)
{
    // double buffer: write ch c -> buf(c&1), ONE barrier, compute from buf(c&1).
    // Writes of ch c+2 (same buffer) are ordered after everyone's compute of ch c
    // by the c+1 barrier, so the second per-channel barrier is gone.
    __shared__ float smA[SMSZ];
    __shared__ float smB[SMSZ];

    const int tx = threadIdx.x;   // 0..7  (w / 2)
    const int ty = threadIdx.y;   // 0..7  (h)
    const int tz = threadIdx.z;   // 0..3  (d)
    const int tid = tx + TXD * ty + TXD * TYD * tz;

    const int w0 = blockIdx.x * TW;
    const int h0 = blockIdx.y * TH;
    const int d0 = blockIdx.z * TD;

    // ---- channel-invariant staging source offsets ----
    int off[NR];
    #pragma unroll
    for (int r = 0; r < NR; ++r) {
        const int a = tid + r * NTH;
        const int z   = a / PLANE;
        const int rm  = a - z * PLANE;
        const int y   = rm / HWS;
        const int x   = rm - y * HWS;
        const int sd = d0 - 1 + z;
        const int sh = h0 - 1 + y;
        const int sw = w0 - 1 + x;
        const bool ok = (a < HTOT) && (x < TW + 2) &&
                        ((unsigned)sd < N) && ((unsigned)sh < N) && ((unsigned)sw < N);
        off[r] = ok ? ((sd * N + sh) * N + sw) : -1;
    }

    const int gw = w0 + VX * tx;
    const int fix_base = ((d0 + tz) * N + (h0 + ty)) * N + gw;
    const int lbase = tz * PLANE + ty * HWS + VX * tx;

    float acc[27][VX];
    #pragma unroll
    for (int s = 0; s < 27; ++s)
        #pragma unroll
        for (int v = 0; v < VX; ++v) acc[s][v] = 0.0f;

    // ---- prologue: prefetch channel 0 ----
    float st[NR];
    #pragma unroll
    for (int r = 0; r < NR; ++r)
        st[r] = (off[r] >= 0) ? movingp[off[r]] : 0.0f;
    float2 fcur = *(const float2*)&fixedp[fix_base];
    float2 fnext = fcur;

    auto step = [&](int c, float* __restrict__ smw) {
        // commit channel c to LDS (vmcnt wait here was covered by prior compute)
        #pragma unroll
        for (int r = 0; r < NR; ++r)
            smw[tid + r * NTH] = st[r];

        // prefetch channel c+1 while this channel is computed
        if (c + 1 < C_CH) {
            const float* mnext = movingp + (size_t)(c + 1) * NNN;
            #pragma unroll
            for (int r = 0; r < NR; ++r)
                st[r] = (off[r] >= 0) ? mnext[off[r]] : 0.0f;
            fnext = *(const float2*)&fixedp[(size_t)(c + 1) * NNN + fix_base];
        }

        __syncthreads();   // single barrier per channel

        const float fv0 = fcur.x;
        const float fv1 = fcur.y;
        #pragma unroll
        for (int i = 0; i < 3; ++i) {
            #pragma unroll
            for (int j = 0; j < 3; ++j) {
                const float* row = &smw[lbase + i * PLANE + j * HWS];
                float wv[VX + 2];
                #pragma unroll
                for (int m = 0; m < VX + 2; ++m) wv[m] = row[m];
                #pragma unroll
                for (int k = 0; k < 3; ++k) {
                    acc[(i * 3 + j) * 3 + k][0] += fv0 * wv[k];
                    acc[(i * 3 + j) * 3 + k][1] += fv1 * wv[k + 1];
                }
            }
        }
        fcur = fnext;
    };

    for (int c = 0; c < C_CH; c += 2) {
        step(c, smA);
        step(c + 1, smB);
    }

    const float scale = 0.17677669529663687f; // 32^-0.5
    #pragma unroll
    for (int s = 0; s < 27; ++s) {
        float2 o;
        o.x = acc[s][0] * scale;
        o.y = acc[s][1] * scale;
        *(float2*)&outp[(size_t)s * NNN + fix_base] = o;
    }
}

extern "C" void kernel_launch(void* const* d_in, const int* in_sizes, int n_in,
                              void* d_out, int out_size, void* d_ws, size_t ws_size,
                              hipStream_t stream) {
    const float* fixedp  = (const float*)d_in[0];
    const float* movingp = (const float*)d_in[1];
    float* outp = (float*)d_out;

    dim3 block(TXD, TYD, TZD);                    // 8 x 8 x 4 = 256
    dim3 grid(N / TW, N / TH, N / TD);            // 6 x 12 x 24 = 1728
    wincorr_kernel<<<grid, block, 0, stream>>>(fixedp, movingp, outp);
}

// Round 3
// 280.996 us; speedup vs baseline: 1.0739x; 1.0739x over previous
//
#include <hip/hip_runtime.h>

#define N 96
#define NNN (N * N * N)
#define C_CH 32

// tile geometry: block 8x8x4 = 256 threads, each thread computes 4 voxels along w
// (VX=4 proven best: round-1's VX=2 halved per-wave work -> worse latency hiding,
//  and its HWS=20 stride caused 4-way bank conflicts. HWS=35 is conflict-free.)
#define TXD 8
#define TYD 8
#define TZD 4
#define VX 4
#define TW (TXD * VX)          // 32
#define TH TYD                 // 8
#define TD TZD                 // 4

// halo tile in LDS: 34 x 10 x 6, row padded to 35 (odd stride -> 2-way bank = free)
#define HWS 35
#define HH 10
#define HD 6
#define PLANE (HWS * HH)       // 350
#define HTOT (PLANE * HD)      // 2100
#define NTH (TXD * TYD * TZD)  // 256
#define NR ((HTOT + NTH - 1) / NTH)  // 9 staging rounds
#define SMSZ (NR * NTH)        // 2304 (over-allocated so stores are unconditional)

// native clang vector for nontemporal builtin (HIP float4 is a class type)
typedef float vfloat4 __attribute__((ext_vector_type(4)));

__global__ __launch_bounds__(NTH, 2) void wincorr_kernel(
    const float* __restrict__ fixedp,
    const float* __restrict__ movingp,
    float* __restrict__ outp)
{
    // LDS double buffer + ONE raw barrier per channel.
    // Correctness: compute(c) reads buf(c&1) after barrier B_c and before B_{c+1};
    // writes of channel c+2 into buf(c&1) happen after B_{c+1} in program order,
    // so reads-before-overwrite is ordered by B_{c+1}.
    // CRUCIAL: raw s_barrier (not __syncthreads) -> no vmcnt(0) drain, so the
    // depth-2 global prefetch stays in flight across barriers (T3/T4 idiom).
    __shared__ float smA[SMSZ];
    __shared__ float smB[SMSZ];

    const int tx = threadIdx.x;   // 0..7  (w / 4)
    const int ty = threadIdx.y;   // 0..7  (h)
    const int tz = threadIdx.z;   // 0..3  (d)
    const int tid = tx + TXD * ty + TXD * TYD * tz;

    const int w0 = blockIdx.x * TW;
    const int h0 = blockIdx.y * TH;
    const int d0 = blockIdx.z * TD;

    // ---- channel-invariant staging source offsets ----
    int off[NR];
    #pragma unroll
    for (int r = 0; r < NR; ++r) {
        const int a = tid + r * NTH;
        const int z   = a / PLANE;
        const int rm  = a - z * PLANE;
        const int y   = rm / HWS;
        const int x   = rm - y * HWS;
        const int sd = d0 - 1 + z;
        const int sh = h0 - 1 + y;
        const int sw = w0 - 1 + x;
        const bool ok = (a < HTOT) && (x < TW + 2) &&
                        ((unsigned)sd < N) && ((unsigned)sh < N) && ((unsigned)sw < N);
        off[r] = ok ? ((sd * N + sh) * N + sw) : -1;
    }

    const int gw = w0 + VX * tx;
    const int fix_base = ((d0 + tz) * N + (h0 + ty)) * N + gw;
    const int lbase = tz * PLANE + ty * HWS + VX * tx;

    float acc[27][VX];
    #pragma unroll
    for (int s = 0; s < 27; ++s)
        #pragma unroll
        for (int v = 0; v < VX; ++v) acc[s][v] = 0.0f;

    // ---- prologue: depth-2 prefetch (channels 0 and 1 both in flight) ----
    float st0[NR], st1[NR];
    #pragma unroll
    for (int r = 0; r < NR; ++r)
        st0[r] = (off[r] >= 0) ? movingp[off[r]] : 0.0f;
    float4 f0 = *(const float4*)&fixedp[fix_base];
    {
        const float* m1 = movingp + (size_t)NNN;
        #pragma unroll
        for (int r = 0; r < NR; ++r)
            st1[r] = (off[r] >= 0) ? m1[off[r]] : 0.0f;
    }
    float4 f1 = *(const float4*)&fixedp[(size_t)NNN + fix_base];

    auto step = [&](int c, float* __restrict__ smw, float (&st)[NR], float4& f) {
        // commit channel c to LDS. The compiler emits a COUNTED s_waitcnt vmcnt(N)
        // here (waits only for st's loads; the other register set's loads for c+1
        // remain outstanding).
        #pragma unroll
        for (int r = 0; r < NR; ++r)
            smw[tid + r * NTH] = st[r];

        // snapshot fixed operand before its registers are reissued
        const float fv[VX] = {f.x, f.y, f.z, f.w};

        // issue channel c+2 into the just-freed register set (depth-2 pipeline:
        // these have two full compute phases + two barriers to complete)
        if (c + 2 < C_CH) {
            const float* mn = movingp + (size_t)(c + 2) * NNN;
            #pragma unroll
            for (int r = 0; r < NR; ++r)
                st[r] = (off[r] >= 0) ? mn[off[r]] : 0.0f;
            f = *(const float4*)&fixedp[(size_t)(c + 2) * NNN + fix_base];
        }

        // make this wave's LDS writes visible, then raw barrier.
        // NO vmcnt drain -> global prefetch survives the barrier.
        asm volatile("s_waitcnt lgkmcnt(0)" ::: "memory");
        __builtin_amdgcn_s_barrier();
        asm volatile("" ::: "memory");

        // compute: 9 rows x 6-float sliding window, 27 taps x 4 voxels
        #pragma unroll
        for (int i = 0; i < 3; ++i) {
            #pragma unroll
            for (int j = 0; j < 3; ++j) {
                const float* row = &smw[lbase + i * PLANE + j * HWS];
                float wv[VX + 2];
                #pragma unroll
                for (int m = 0; m < VX + 2; ++m) wv[m] = row[m];
                #pragma unroll
                for (int k = 0; k < 3; ++k)
                    #pragma unroll
                    for (int v = 0; v < VX; ++v)
                        acc[(i * 3 + j) * 3 + k][v] += fv[v] * wv[v + k];
            }
        }
    };

    for (int c = 0; c < C_CH; c += 2) {
        step(c,     smA, st0, f0);
        step(c + 1, smB, st1, f1);
    }

    const float scale = 0.17677669529663687f; // 32^-0.5
    #pragma unroll
    for (int s = 0; s < 27; ++s) {
        vfloat4 o;
        o.x = acc[s][0] * scale;
        o.y = acc[s][1] * scale;
        o.z = acc[s][2] * scale;
        o.w = acc[s][3] * scale;
        // write-once output: nontemporal keeps the moving slab resident in L2
        __builtin_nontemporal_store(o, (vfloat4*)&outp[(size_t)s * NNN + fix_base]);
    }
}

extern "C" void kernel_launch(void* const* d_in, const int* in_sizes, int n_in,
                              void* d_out, int out_size, void* d_ws, size_t ws_size,
                              hipStream_t stream) {
    const float* fixedp  = (const float*)d_in[0];
    const float* movingp = (const float*)d_in[1];
    float* outp = (float*)d_out;

    dim3 block(TXD, TYD, TZD);                    // 8 x 8 x 4 = 256
    dim3 grid(N / TW, N / TH, N / TD);            // 3 x 12 x 24 = 864
    wincorr_kernel<<<grid, block, 0, stream>>>(fixedp, movingp, outp);
}